// Round 11
// baseline (334.143 us; speedup 1.0000x reference)
//
#include <hip/hip_runtime.h>

// Spatially varying anisotropic 2D elastic wave sim, 384x384, 192 steps.
// Round 18: inter-block convoy overlap test. R15 body (DPP column
// exchange, full unroll, register sigv, lgkm-only barrier, wide float4
// coeff/state) with geometry OWN=16, HALO=K=8, TS=32, 512 thr (8 waves,
// 32 rows x 16 lanes, 1 row x 2 cols per thread), grid 24x24 = 576
// blocks ~= 2.25/CU -> 2 blocks RESIDENT per CU (launch_bounds(512,4)
// caps VGPR 128; LDS 16.9KB):
//  - theory: per-step ~1.2us is a per-block convoy (barrier -> LDS read
//    burst -> dep chain -> publish -> barrier) that no within-block
//    lever dents (R13 LDS -3%, R14/15 occupancy +20% then flat, R16 I$
//    -30us WORSE, R17 issue-cut null). Two independent blocks per CU
//    overlap: block A's barrier stall = block B's issue window.
//  - R11's old multi-block null was confounded (scratch sigv bug,
//    launch-bounds spills) -- post-fix this axis was never probed.
//  - 24 launches (+18us vs 16) is the accepted price.

typedef float v2f __attribute__((ext_vector_type(2)));

#define NXg 384
#define NYg 384
#define NPT (NXg * NYg)
#define NFRAMES 48

#define OWN 16
#define HALO 8
#define TS 32
#define KSTEPS 8
#define NLAUNCH 24
#define NTH 512          // 32 rows x 16 lanes, 8 waves

#define H_   1e-4
#define DT_  5e-9
#define RHO_ 1610.0

#define B11_LO 5e10f
#define B11_HI 2.5e11f
#define B22_LO 5e9f
#define B22_HI 5e10f
#define B12_LO 5e9f
#define B12_HI 5e10f
#define B16_LO 0.0f
#define B16_HI 6e10f
#define B26_LO 0.0f
#define B26_HI 2e10f
#define B66_LO 5e9f
#define B66_HI 3e10f

#define ROW_SHR1 0x111   // dst[lane] = src[lane-1] within 16-lane row
#define ROW_SHL1 0x101   // dst[lane] = src[lane+1] within 16-lane row

static __device__ __constant__ float kScale  = (float)(DT_ * DT_ / (H_ * H_) / RHO_);
static __device__ __constant__ float kSrcScl = (float)(DT_ * DT_ / RHO_);

__device__ __forceinline__ float clipf(float v, float lo, float hi) {
    return fminf(fmaxf(v, lo), hi);
}
__device__ __forceinline__ v2f vfma(v2f a, v2f b, v2f c) {
    return __builtin_elementwise_fma(a, b, c);
}
__device__ __forceinline__ v2f vbc(float s) { v2f r; r[0] = s; r[1] = s; return r; }
__device__ __forceinline__ v2f vswap(v2f a) { return __builtin_shufflevector(a, a, 1, 0); }

// in-wave halo import: neighbor lane's v2f via 2x v_mov_dpp.
// Invalid lanes (16-lane-row edge) receive 'oldv' == the rim-clamp value.
template <int CTRL>
__device__ __forceinline__ v2f dpp_shift(v2f oldv, v2f src) {
    union { v2f v; int i[2]; } o, s, r;
    o.v = oldv; s.v = src;
    r.i[0] = __builtin_amdgcn_update_dpp(o.i[0], s.i[0], CTRL, 0xf, 0xf, false);
    r.i[1] = __builtin_amdgcn_update_dpp(o.i[1], s.i[1], CTRL, 0xf, 0xf, false);
    return r.v;
}

// barrier that only waits LDS (no vmcnt drain); memory clobber pins ordering
#define LDS_BARRIER() asm volatile("s_waitcnt lgkmcnt(0)\n\ts_barrier" ::: "memory")

// ws float layout:
// [0..4NPT):   C0 = float4{A11, A22, A12p66, A16}  (pre-scaled)
// [4NPT..8NPT):C1 = float4{A26, A66, GS, 0}
// [8NPT..12NPT):  state set0: float4{cur.x, cur.y, old.x, old.y}
// [12NPT..16NPT): state set1

__global__ __launch_bounds__(256)
void setup_kernel(const float* __restrict__ lc11, const float* __restrict__ lc12,
                  const float* __restrict__ lc16, const float* __restrict__ lc22,
                  const float* __restrict__ lc26, const float* __restrict__ lc66,
                  const float* __restrict__ gauss, float* __restrict__ ws) {
    int i = blockIdx.x * blockDim.x + threadIdx.x;
    if (i >= NPT) return;
    float C11 = clipf(expf(lc11[i]), B11_LO, B11_HI);
    float C12 = clipf(expf(lc12[i]), B12_LO, B12_HI);
    float C16 = clipf(expf(lc16[i]), B16_LO, B16_HI);
    float C22 = clipf(expf(lc22[i]), B22_LO, B22_HI);
    float C26 = clipf(expf(lc26[i]), B26_LO, B26_HI);
    float C66 = clipf(expf(lc66[i]), B66_LO, B66_HI);
    float s = kScale;
    float4* C0 = (float4*)ws;
    float4* C1 = (float4*)(ws + 4 * (size_t)NPT);
    C0[i] = make_float4(C11 * s, C22 * s, (C12 + C66) * s, C16 * s);
    C1[i] = make_float4(C26 * s, C66 * s, gauss[i] * kSrcScl, 0.0f);
    float4* s0 = (float4*)(ws + 8 * (size_t)NPT);
    s0[i] = make_float4(0.0f, 0.0f, 0.0f, 0.0f);
}

__global__ __launch_bounds__(NTH, 4)
void fused_kernel(const float* __restrict__ ws, const float* __restrict__ sig,
                  const float4* __restrict__ inS, float4* __restrict__ outS,
                  float* __restrict__ out, int L) {
    __shared__ v2f sb[2][TS][TS + 1];

    const int tid = threadIdx.x;
    const int tx = tid >> 4;          // 0..31 cell row
    const int ty = tid & 15;          // 0..15, 2 cells wide each
    const int r0 = tx;
    const int c0 = 2 * ty;
    const int gx0 = blockIdx.y * OWN - HALO;
    const int gy0 = blockIdx.x * OWN - HALO;

    const float4* __restrict__ C0 = (const float4*)ws;
    const float4* __restrict__ C1 = (const float4*)(ws + 4 * (size_t)NPT);

    v2f cur[2], old_[2];
    v2f ca[2], cb[2];                       // {A11,A66}, {A66,A22}
    float a12p66[2], a16[2], a26[2], gs[2];
    int gidx[2];

#pragma unroll
    for (int j = 0; j < 2; ++j) {
        int gx = gx0 + r0;
        int gy = gy0 + c0 + j;
        bool d = (unsigned)gx < (unsigned)NXg && (unsigned)gy < (unsigned)NYg;
        int g = d ? gx * NYg + gy : 0;
        gidx[j] = g;
        float4 st = d ? inS[g] : make_float4(0, 0, 0, 0);
        v2f c; c[0] = st.x; c[1] = st.y;
        v2f o; o[0] = st.z; o[1] = st.w;
        cur[j] = c; old_[j] = o;
        float4 k0 = d ? C0[g] : make_float4(0, 0, 0, 0);
        float4 k1 = d ? C1[g] : make_float4(0, 0, 0, 0);
        v2f t; t[0] = k0.x; t[1] = k1.y; ca[j] = t;   // {A11, A66}
        v2f u; u[0] = k1.y; u[1] = k0.y; cb[j] = u;   // {A66, A22}
        a12p66[j] = k0.z; a16[j] = k0.w; a26[j] = k1.x; gs[j] = k1.z;
    }

    // preload all step source values; step loop FULLY UNROLLED -> registers
    const int t0 = L * KSTEPS;
    float sigv[KSTEPS];
#pragma unroll
    for (int k = 0; k < KSTEPS; ++k) sigv[k] = sig[t0 + k];

    // clamped vertical halo rows (trapezoid garbage-tolerance at rim)
    const int rm = (r0 > 0) ? r0 - 1 : 0;
    const int rp = (r0 + 1 < TS) ? r0 + 1 : TS - 1;

    // owned core: rows [8,24) -> tx in [8,24); cols [8,24) -> ty in [4,12)
    const bool owned = (tx >= 8) && (tx < 24) && (ty >= 4) && (ty < 12);

    // publish initial values into buffer 0
    sb[0][r0][c0] = cur[0];
    sb[0][r0][c0 + 1] = cur[1];
    LDS_BARRIER();

    v2f c20; c20[0] = 2.0f; c20[1] = 0.0f;
    v2f c02; c02[0] = 0.0f; c02[1] = 2.0f;
    const v2f m2 = vbc(-2.0f);
    const v2f qt = vbc(0.25f);
    const v2f two = vbc(2.0f);

#pragma unroll
    for (int s = 1; s <= KSTEPS; ++s) {
        const v2f (*rb)[TS + 1] = sb[(s - 1) & 1];
        v2f (*wb)[TS + 1] = sb[s & 1];
        v2f vsig; vsig[0] = 0.0f; vsig[1] = sigv[s - 1];

        // 3x4 window: own row + DPP side cols; rows +-1 from LDS (4 b64)
        // with their side cols via DPP of the loaded values.
        v2f vm[4], vc[4], vp[4];
        vc[1] = cur[0]; vc[2] = cur[1];
        vc[0] = dpp_shift<ROW_SHR1>(cur[0], cur[1]);
        vc[3] = dpp_shift<ROW_SHL1>(cur[1], cur[0]);
        {
            v2f a0 = rb[rm][c0], a1 = rb[rm][c0 + 1];
            vm[1] = a0; vm[2] = a1;
            vm[0] = dpp_shift<ROW_SHR1>(a0, a1);
            vm[3] = dpp_shift<ROW_SHL1>(a1, a0);
        }
        {
            v2f b0 = rb[rp][c0], b1 = rb[rp][c0 + 1];
            vp[1] = b0; vp[2] = b1;
            vp[0] = dpp_shift<ROW_SHR1>(b0, b1);
            vp[3] = dpp_shift<ROW_SHL1>(b1, b0);
        }

        // horizontal differences for cross-derivs (rows rm, rp only)
        v2f dhm[2], dhp[2];
#pragma unroll
        for (int j = 0; j < 2; ++j) {
            dhm[j] = vm[j + 2] - vm[j];
            dhp[j] = vp[j + 2] - vp[j];
        }

#pragma unroll
        for (int j = 0; j < 2; ++j) {
            v2f c = vc[j + 1];
            v2f sxx = vfma(m2, c, vm[j + 1] + vp[j + 1]);  // pk
            v2f syy = vfma(m2, c, vc[j] + vc[j + 2]);      // pk
            v2f sxy = qt * (dhp[j] - dhm[j]);              // pk

            // t4 = {2*sxy.x + sxx.y, sxx.x}; t5 = {syy.y, 2*sxy.y + syy.x}
            v2f t4 = vfma(c20, vbc(sxy[0]), vswap(sxx));
            v2f t5 = vfma(c02, vbc(sxy[1]), vswap(syy));
            // L = {lux, luy}
            v2f Lv = ca[j] * sxx;
            Lv = vfma(cb[j], syy, Lv);
            Lv = vfma(vbc(a12p66[j]), vswap(sxy), Lv);
            Lv = vfma(vbc(a16[j]), t4, Lv);
            Lv = vfma(vbc(a26[j]), t5, Lv);
            // source on y only: {lux, sig*gs + luy} (exact: 0*gs+lux)
            Lv = vfma(vsig, vbc(gs[j]), Lv);
            // n = fma(2, c, L) - old
            v2f n = vfma(two, c, Lv) - old_[j];
            old_[j] = c;
            cur[j] = n;
        }

        // frame output at global t = t0 + s - 1; t%4==3 <=> s%4==0
        // (fire-and-forget: the step barrier does NOT drain vmcnt)
        if ((s & 3) == 0 && owned) {
            int f = 2 * L + (s >> 2) - 1;
            float* oux = out + (size_t)f * NPT;
            float* ouy = out + (size_t)(NFRAMES + f) * NPT;
#pragma unroll
            for (int j = 0; j < 2; ++j) {
                oux[gidx[j]] = cur[j][0];
                ouy[gidx[j]] = cur[j][1];
            }
        }

        // publish new values; final step's publish + barrier are dead
        if (s < KSTEPS) {
            wb[r0][c0] = cur[0];
            wb[r0][c0 + 1] = cur[1];
            LDS_BARRIER();
        }
    }

    if (owned) {
#pragma unroll
        for (int j = 0; j < 2; ++j) {
            float4 st = make_float4(cur[j][0], cur[j][1], old_[j][0], old_[j][1]);
            outS[gidx[j]] = st;
        }
    }
}

extern "C" void kernel_launch(void* const* d_in, const int* in_sizes, int n_in,
                              void* d_out, int out_size, void* d_ws, size_t ws_size,
                              hipStream_t stream) {
    const float* lc11  = (const float*)d_in[0];
    const float* lc12  = (const float*)d_in[1];
    const float* lc16  = (const float*)d_in[2];
    const float* lc22  = (const float*)d_in[3];
    const float* lc26  = (const float*)d_in[4];
    const float* lc66  = (const float*)d_in[5];
    const float* gauss = (const float*)d_in[6];
    const float* sig   = (const float*)d_in[7];

    float* ws  = (float*)d_ws;
    float* out = (float*)d_out;

    setup_kernel<<<(NPT + 255) / 256, 256, 0, stream>>>(lc11, lc12, lc16, lc22,
                                                        lc26, lc66, gauss, ws);

    float4* set0 = (float4*)(ws + 8 * (size_t)NPT);
    float4* set1 = (float4*)(ws + 12 * (size_t)NPT);

    dim3 grid(NXg / OWN, NYg / OWN);  // 24x24 = 576 blocks, ~2.25/CU
    for (int L = 0; L < NLAUNCH; ++L) {
        float4* iS = (L & 1) ? set1 : set0;
        float4* oS = (L & 1) ? set0 : set1;
        fused_kernel<<<grid, NTH, 0, stream>>>(ws, sig, iS, oS, out, L);
    }
}

// Round 12
// 315.838 us; speedup vs baseline: 1.0580x; 1.0580x over previous
//
#include <hip/hip_runtime.h>

// Spatially varying anisotropic 2D elastic wave sim, 384x384, 192 steps.
// Round 19: BARRIER-FREE wave-ripple stepping on the R15 base (best 293.4us:
// 48x48 tile, OWN=24, K=12, 16 launches, 768 thr = 12 waves of 4 rows,
// 3x1 cells/thread, DPP column exchange, full unroll, register sigv).
// Ledger finding: per-barrier-period cost is ~1.35us FLAT across every
// config (waves, LDS volume, issue volume, I$, blocks/CU) -> the block-wide
// per-step s_barrier convoy IS the floor. This round removes it:
//  - wave w only depends on waves w+-1 (its rows +-1). Per-step sync is a
//    per-wave handshake: publish rows -> s_waitcnt lgkmcnt(0) -> flag
//    cnt[w]=s+1 (single writer); reader polls cnt[w+-1] >= s before
//    reading neighbor rows. Waves skew into a pipeline; no convoy.
//  - TRIPLE-buffered sb: with the poll invariant (neighbors >= s-1 when
//    wave w is at s), the only concurrent reader of buf s%3 while w
//    writes it is a neighbor at s+1, gated on cnt[w] >= s (write drained
//    before flag). 2 buffers would collide at sigma=s-1; 3 are safe.
//  - DS ordering is writer-side (lgkmcnt(0) before flag), so reader
//    visibility is unconditional; poll is wave-uniform (no divergence),
//    broadcast LDS reads (no bank conflicts), s_sleep in the spin.
//  - ONE __syncthreads() at init (publish buf0 + flags=1); zero barriers
//    in the 12-step loop.
// LDS: 3*48*49*8 = 56.4KB + 12 flags -> 1 block/CU (unchanged).

typedef float v2f __attribute__((ext_vector_type(2)));

#define NXg 384
#define NYg 384
#define NPT (NXg * NYg)
#define NFRAMES 48

#define OWN 24
#define HALO 12
#define TS 48
#define KSTEPS 12
#define NLAUNCH 16
#define NTH 768          // 16 lanes x 48 rows, 12 waves (4 rows/wave)
#define NW 12

#define H_   1e-4
#define DT_  5e-9
#define RHO_ 1610.0

#define B11_LO 5e10f
#define B11_HI 2.5e11f
#define B22_LO 5e9f
#define B22_HI 5e10f
#define B12_LO 5e9f
#define B12_HI 5e10f
#define B16_LO 0.0f
#define B16_HI 6e10f
#define B26_LO 0.0f
#define B26_HI 2e10f
#define B66_LO 5e9f
#define B66_HI 3e10f

#define ROW_SHR1 0x111   // dst[lane] = src[lane-1] within 16-lane row
#define ROW_SHL1 0x101   // dst[lane] = src[lane+1] within 16-lane row

static __device__ __constant__ float kScale  = (float)(DT_ * DT_ / (H_ * H_) / RHO_);
static __device__ __constant__ float kSrcScl = (float)(DT_ * DT_ / RHO_);

__device__ __forceinline__ float clipf(float v, float lo, float hi) {
    return fminf(fmaxf(v, lo), hi);
}
__device__ __forceinline__ v2f vfma(v2f a, v2f b, v2f c) {
    return __builtin_elementwise_fma(a, b, c);
}
__device__ __forceinline__ v2f vbc(float s) { v2f r; r[0] = s; r[1] = s; return r; }
__device__ __forceinline__ v2f vswap(v2f a) { return __builtin_shufflevector(a, a, 1, 0); }

template <int CTRL>
__device__ __forceinline__ v2f dpp_shift(v2f oldv, v2f src) {
    union { v2f v; int i[2]; } o, s, r;
    o.v = oldv; s.v = src;
    r.i[0] = __builtin_amdgcn_update_dpp(o.i[0], s.i[0], CTRL, 0xf, 0xf, false);
    r.i[1] = __builtin_amdgcn_update_dpp(o.i[1], s.i[1], CTRL, 0xf, 0xf, false);
    return r.v;
}

// drain this wave's own DS ops; compiler memory fence pins ordering
#define LGKM_DRAIN() asm volatile("s_waitcnt lgkmcnt(0)" ::: "memory")

// ws float layout:
// [0..4NPT):   C0 = float4{A11, A22, A12p66, A16}  (pre-scaled)
// [4NPT..8NPT):C1 = float4{A26, A66, GS, 0}
// [8NPT..12NPT):  state set0: float4{cur.x, cur.y, old.x, old.y}
// [12NPT..16NPT): state set1

__global__ __launch_bounds__(256)
void setup_kernel(const float* __restrict__ lc11, const float* __restrict__ lc12,
                  const float* __restrict__ lc16, const float* __restrict__ lc22,
                  const float* __restrict__ lc26, const float* __restrict__ lc66,
                  const float* __restrict__ gauss, float* __restrict__ ws) {
    int i = blockIdx.x * blockDim.x + threadIdx.x;
    if (i >= NPT) return;
    float C11 = clipf(expf(lc11[i]), B11_LO, B11_HI);
    float C12 = clipf(expf(lc12[i]), B12_LO, B12_HI);
    float C16 = clipf(expf(lc16[i]), B16_LO, B16_HI);
    float C22 = clipf(expf(lc22[i]), B22_LO, B22_HI);
    float C26 = clipf(expf(lc26[i]), B26_LO, B26_HI);
    float C66 = clipf(expf(lc66[i]), B66_LO, B66_HI);
    float s = kScale;
    float4* C0 = (float4*)ws;
    float4* C1 = (float4*)(ws + 4 * (size_t)NPT);
    C0[i] = make_float4(C11 * s, C22 * s, (C12 + C66) * s, C16 * s);
    C1[i] = make_float4(C26 * s, C66 * s, gauss[i] * kSrcScl, 0.0f);
    float4* s0 = (float4*)(ws + 8 * (size_t)NPT);
    s0[i] = make_float4(0.0f, 0.0f, 0.0f, 0.0f);
}

__global__ __launch_bounds__(NTH)
void fused_kernel(const float* __restrict__ ws, const float* __restrict__ sig,
                  const float4* __restrict__ inS, float4* __restrict__ outS,
                  float* __restrict__ out, int L) {
    __shared__ v2f sb[3][TS][TS + 1];
    __shared__ int cnt[NW];

    const int tid = threadIdx.x;
    const int tx = tid >> 4;          // 0..47 cell row
    const int ty = tid & 15;          // 0..15, 3 cells wide each
    const int r0 = tx;
    const int c0 = 3 * ty;
    const int W  = tx >> 2;           // wave index 0..11 (4 rows/wave)
    const int gx0 = blockIdx.y * OWN - HALO;
    const int gy0 = blockIdx.x * OWN - HALO;

    const float4* __restrict__ C0 = (const float4*)ws;
    const float4* __restrict__ C1 = (const float4*)(ws + 4 * (size_t)NPT);

    v2f cur[3], old_[3];
    v2f ca[3], cb[3];                       // {A11,A66}, {A66,A22}
    float a12p66[3], a16[3], a26[3], gs[3];
    int gidx[3];

#pragma unroll
    for (int j = 0; j < 3; ++j) {
        int gx = gx0 + r0;
        int gy = gy0 + c0 + j;
        bool d = (unsigned)gx < (unsigned)NXg && (unsigned)gy < (unsigned)NYg;
        int g = d ? gx * NYg + gy : 0;
        gidx[j] = g;
        float4 st = d ? inS[g] : make_float4(0, 0, 0, 0);
        v2f c; c[0] = st.x; c[1] = st.y;
        v2f o; o[0] = st.z; o[1] = st.w;
        cur[j] = c; old_[j] = o;
        float4 k0 = d ? C0[g] : make_float4(0, 0, 0, 0);
        float4 k1 = d ? C1[g] : make_float4(0, 0, 0, 0);
        v2f t; t[0] = k0.x; t[1] = k1.y; ca[j] = t;   // {A11, A66}
        v2f u; u[0] = k1.y; u[1] = k0.y; cb[j] = u;   // {A66, A22}
        a12p66[j] = k0.z; a16[j] = k0.w; a26[j] = k1.x; gs[j] = k1.z;
    }

    // preload all step source values; step loop FULLY UNROLLED -> registers
    const int t0 = L * KSTEPS;
    float sigv[KSTEPS];
#pragma unroll
    for (int k = 0; k < KSTEPS; ++k) sigv[k] = sig[t0 + k];

    // clamped vertical halo rows (trapezoid garbage-tolerance at rim)
    const int rm = (r0 > 0) ? r0 - 1 : 0;
    const int rp = (r0 + 1 < TS) ? r0 + 1 : TS - 1;

    // owned core: rows [12,36) -> tx in [12,36); cols [12,36) -> ty in [4,12)
    const bool owned = (tx >= 12) && (tx < 36) && (ty >= 4) && (ty < 12);

    // init: publish state into buffer 0, raise own flag, ONE barrier.
#pragma unroll
    for (int j = 0; j < 3; ++j)
        sb[0][r0][c0 + j] = cur[j];
    LGKM_DRAIN();
    if ((tid & 63) == 0) *((volatile int*)&cnt[W]) = 1;
    __syncthreads();   // everyone sees buf0 rows + all flags = 1

    v2f c20; c20[0] = 2.0f; c20[1] = 0.0f;
    v2f c02; c02[0] = 0.0f; c02[1] = 2.0f;
    const v2f m2 = vbc(-2.0f);
    const v2f qt = vbc(0.25f);
    const v2f two = vbc(2.0f);

    volatile int* vcnt = (volatile int*)cnt;

#pragma unroll
    for (int s = 1; s <= KSTEPS; ++s) {
        const v2f (*rb)[TS + 1] = sb[(s - 1) % 3];
        v2f (*wb)[TS + 1] = sb[s % 3];
        v2f vsig; vsig[0] = 0.0f; vsig[1] = sigv[s - 1];

        // per-wave ripple handshake: wait until neighbor waves have
        // published their step-(s-1) rows. Wave-uniform branch + spin;
        // broadcast LDS reads (same addr all lanes).
        if (W > 0 && W < NW - 1) {
            while (vcnt[W - 1] < s || vcnt[W + 1] < s) __builtin_amdgcn_s_sleep(1);
        } else if (W == 0) {
            while (vcnt[1] < s) __builtin_amdgcn_s_sleep(1);
        } else {
            while (vcnt[NW - 2] < s) __builtin_amdgcn_s_sleep(1);
        }
        LGKM_DRAIN();   // order: poll completes before row reads issue

        // 3x5 window: own row + DPP side cols; rows +-1 from LDS (6 b64)
        v2f vm[5], vc[5], vp[5];
        vc[1] = cur[0]; vc[2] = cur[1]; vc[3] = cur[2];
        vc[0] = dpp_shift<ROW_SHR1>(cur[0], cur[2]);
        vc[4] = dpp_shift<ROW_SHL1>(cur[2], cur[0]);
        {
            v2f a0 = rb[rm][c0], a1 = rb[rm][c0 + 1], a2 = rb[rm][c0 + 2];
            vm[1] = a0; vm[2] = a1; vm[3] = a2;
            vm[0] = dpp_shift<ROW_SHR1>(a0, a2);
            vm[4] = dpp_shift<ROW_SHL1>(a2, a0);
        }
        {
            v2f b0 = rb[rp][c0], b1 = rb[rp][c0 + 1], b2 = rb[rp][c0 + 2];
            vp[1] = b0; vp[2] = b1; vp[3] = b2;
            vp[0] = dpp_shift<ROW_SHR1>(b0, b2);
            vp[4] = dpp_shift<ROW_SHL1>(b2, b0);
        }

        // horizontal differences for cross-derivs (rows rm, rp only)
        v2f dhm[3], dhp[3];
#pragma unroll
        for (int j = 0; j < 3; ++j) {
            dhm[j] = vm[j + 2] - vm[j];
            dhp[j] = vp[j + 2] - vp[j];
        }

#pragma unroll
        for (int j = 0; j < 3; ++j) {
            v2f c = vc[j + 1];
            v2f sxx = vfma(m2, c, vm[j + 1] + vp[j + 1]);  // pk
            v2f syy = vfma(m2, c, vc[j] + vc[j + 2]);      // pk
            v2f sxy = qt * (dhp[j] - dhm[j]);              // pk

            // t4 = {2*sxy.x + sxx.y, sxx.x}; t5 = {syy.y, 2*sxy.y + syy.x}
            v2f t4 = vfma(c20, vbc(sxy[0]), vswap(sxx));
            v2f t5 = vfma(c02, vbc(sxy[1]), vswap(syy));
            // L = {lux, luy}
            v2f Lv = ca[j] * sxx;
            Lv = vfma(cb[j], syy, Lv);
            Lv = vfma(vbc(a12p66[j]), vswap(sxy), Lv);
            Lv = vfma(vbc(a16[j]), t4, Lv);
            Lv = vfma(vbc(a26[j]), t5, Lv);
            // source on y only: {lux, sig*gs + luy} (exact: 0*gs+lux)
            Lv = vfma(vsig, vbc(gs[j]), Lv);
            // n = fma(2, c, L) - old
            v2f n = vfma(two, c, Lv) - old_[j];
            old_[j] = c;
            cur[j] = n;
        }

        // frame output at global t = t0 + s - 1; t%4==3 <=> s%4==0
        if ((s & 3) == 0 && owned) {
            int f = 3 * L + (s >> 2) - 1;
            float* oux = out + (size_t)f * NPT;
            float* ouy = out + (size_t)(NFRAMES + f) * NPT;
#pragma unroll
            for (int j = 0; j < 3; ++j) {
                oux[gidx[j]] = cur[j][0];
                ouy[gidx[j]] = cur[j][1];
            }
        }

        // publish new values; drain OWN writes; raise flag (single writer).
        // Readers of buf s%3 (neighbors at step s+1) are gated on the flag.
        if (s < KSTEPS) {
#pragma unroll
            for (int j = 0; j < 3; ++j)
                wb[r0][c0 + j] = cur[j];
            LGKM_DRAIN();
            if ((tid & 63) == 0) vcnt[W] = s + 1;
        }
    }

    if (owned) {
#pragma unroll
        for (int j = 0; j < 3; ++j) {
            float4 st = make_float4(cur[j][0], cur[j][1], old_[j][0], old_[j][1]);
            outS[gidx[j]] = st;
        }
    }
}

extern "C" void kernel_launch(void* const* d_in, const int* in_sizes, int n_in,
                              void* d_out, int out_size, void* d_ws, size_t ws_size,
                              hipStream_t stream) {
    const float* lc11  = (const float*)d_in[0];
    const float* lc12  = (const float*)d_in[1];
    const float* lc16  = (const float*)d_in[2];
    const float* lc22  = (const float*)d_in[3];
    const float* lc26  = (const float*)d_in[4];
    const float* lc66  = (const float*)d_in[5];
    const float* gauss = (const float*)d_in[6];
    const float* sig   = (const float*)d_in[7];

    float* ws  = (float*)d_ws;
    float* out = (float*)d_out;

    setup_kernel<<<(NPT + 255) / 256, 256, 0, stream>>>(lc11, lc12, lc16, lc22,
                                                        lc26, lc66, gauss, ws);

    float4* set0 = (float4*)(ws + 8 * (size_t)NPT);
    float4* set1 = (float4*)(ws + 12 * (size_t)NPT);

    dim3 grid(NXg / OWN, NYg / OWN);  // 16x16 = 256 blocks, 1 per CU, 12 waves
    for (int L = 0; L < NLAUNCH; ++L) {
        float4* iS = (L & 1) ? set1 : set0;
        float4* oS = (L & 1) ? set0 : set1;
        fused_kernel<<<grid, NTH, 0, stream>>>(ws, sig, iS, oS, out, L);
    }
}

// Round 13
// 295.431 us; speedup vs baseline: 1.1310x; 1.0691x over previous
//
#include <hip/hip_runtime.h>

// Spatially varying anisotropic 2D elastic wave sim, 384x384, 192 steps.
// Round 20: RESTORE R15 (best known, 293.4us) as the closing kernel.
// Session ledger (per-sync-period cost ~1.33-1.46us in EVERY structure):
//  - R12 full-unroll + reg sigv (scratch bug fix): 354 -> 327
//  - R13 DPP column exchange (-33% LDS ops):        327 -> 319
//  - R14 9 waves (2.25/SIMD):                       319 -> 299
//  - R15 12 waves + 3x1 cells + DPP (this kernel):  299 -> 293.4  BEST
//  - R16 rolled loop (I$ test):      323 (worse -> I$ exonerated)
//  - R17 live-trapezoid issue cut:   296 (null -> issue exonerated)
//  - R18 2 blocks/CU (TS=32):        334 (halo economics dominate)
//  - R19 barrier-free wave ripple:   316 (poll latency > barrier cost)
// Remaining ~0.8us/period stall is unattributable with available
// counters (barrier+LDS round-trip convoy vs DVFS); all structural
// levers probed with pre-registered predictions came back null/worse.
//
// Structure: OWN=24, HALO=K=12, TS=48, grid 16x16=256 blocks (1/CU),
// 768 thr = 12 waves (16 lanes x 48 rows, 3x1 cells/thread), 16
// launches, packed v2f LDS + pk stencil math, wide float4 coeff/state,
// DPP in-wave column halo, lgkm-only step barrier, full unroll,
// register sigv, fire-and-forget frame stores.

typedef float v2f __attribute__((ext_vector_type(2)));

#define NXg 384
#define NYg 384
#define NPT (NXg * NYg)
#define NFRAMES 48

#define OWN 24
#define HALO 12
#define TS 48
#define KSTEPS 12
#define NLAUNCH 16
#define NTH 768          // 16 wide x 48 tall threads, 12 waves
#define TROW 16

#define H_   1e-4
#define DT_  5e-9
#define RHO_ 1610.0

#define B11_LO 5e10f
#define B11_HI 2.5e11f
#define B22_LO 5e9f
#define B22_HI 5e10f
#define B12_LO 5e9f
#define B12_HI 5e10f
#define B16_LO 0.0f
#define B16_HI 6e10f
#define B26_LO 0.0f
#define B26_HI 2e10f
#define B66_LO 5e9f
#define B66_HI 3e10f

#define ROW_SHR1 0x111   // dst[lane] = src[lane-1] within 16-lane row
#define ROW_SHL1 0x101   // dst[lane] = src[lane+1] within 16-lane row

static __device__ __constant__ float kScale  = (float)(DT_ * DT_ / (H_ * H_) / RHO_);
static __device__ __constant__ float kSrcScl = (float)(DT_ * DT_ / RHO_);

__device__ __forceinline__ float clipf(float v, float lo, float hi) {
    return fminf(fmaxf(v, lo), hi);
}
__device__ __forceinline__ v2f vfma(v2f a, v2f b, v2f c) {
    return __builtin_elementwise_fma(a, b, c);
}
__device__ __forceinline__ v2f vbc(float s) { v2f r; r[0] = s; r[1] = s; return r; }
__device__ __forceinline__ v2f vswap(v2f a) { return __builtin_shufflevector(a, a, 1, 0); }

// in-wave halo import: neighbor lane's v2f via 2x v_mov_dpp.
// Invalid lanes (16-lane-row edge) receive 'oldv' == the rim-clamp value.
template <int CTRL>
__device__ __forceinline__ v2f dpp_shift(v2f oldv, v2f src) {
    union { v2f v; int i[2]; } o, s, r;
    o.v = oldv; s.v = src;
    r.i[0] = __builtin_amdgcn_update_dpp(o.i[0], s.i[0], CTRL, 0xf, 0xf, false);
    r.i[1] = __builtin_amdgcn_update_dpp(o.i[1], s.i[1], CTRL, 0xf, 0xf, false);
    return r.v;
}

// barrier that only waits LDS (no vmcnt drain); memory clobber pins ordering
#define LDS_BARRIER() asm volatile("s_waitcnt lgkmcnt(0)\n\ts_barrier" ::: "memory")

// ws float layout:
// [0..4NPT):   C0 = float4{A11, A22, A12p66, A16}  (pre-scaled)
// [4NPT..8NPT):C1 = float4{A26, A66, GS, 0}
// [8NPT..12NPT):  state set0: float4{cur.x, cur.y, old.x, old.y}
// [12NPT..16NPT): state set1

__global__ __launch_bounds__(256)
void setup_kernel(const float* __restrict__ lc11, const float* __restrict__ lc12,
                  const float* __restrict__ lc16, const float* __restrict__ lc22,
                  const float* __restrict__ lc26, const float* __restrict__ lc66,
                  const float* __restrict__ gauss, float* __restrict__ ws) {
    int i = blockIdx.x * blockDim.x + threadIdx.x;
    if (i >= NPT) return;
    float C11 = clipf(expf(lc11[i]), B11_LO, B11_HI);
    float C12 = clipf(expf(lc12[i]), B12_LO, B12_HI);
    float C16 = clipf(expf(lc16[i]), B16_LO, B16_HI);
    float C22 = clipf(expf(lc22[i]), B22_LO, B22_HI);
    float C26 = clipf(expf(lc26[i]), B26_LO, B26_HI);
    float C66 = clipf(expf(lc66[i]), B66_LO, B66_HI);
    float s = kScale;
    float4* C0 = (float4*)ws;
    float4* C1 = (float4*)(ws + 4 * (size_t)NPT);
    C0[i] = make_float4(C11 * s, C22 * s, (C12 + C66) * s, C16 * s);
    C1[i] = make_float4(C26 * s, C66 * s, gauss[i] * kSrcScl, 0.0f);
    float4* s0 = (float4*)(ws + 8 * (size_t)NPT);
    s0[i] = make_float4(0.0f, 0.0f, 0.0f, 0.0f);
}

__global__ __launch_bounds__(NTH)
void fused_kernel(const float* __restrict__ ws, const float* __restrict__ sig,
                  const float4* __restrict__ inS, float4* __restrict__ outS,
                  float* __restrict__ out, int L) {
    __shared__ v2f sb[2][TS][TS + 1];

    const int tid = threadIdx.x;
    const int tx = tid >> 4;          // 0..47 cell row
    const int ty = tid & 15;          // 0..15, 3 cells wide each
    const int r0 = tx;
    const int c0 = 3 * ty;
    const int gx0 = blockIdx.y * OWN - HALO;
    const int gy0 = blockIdx.x * OWN - HALO;

    const float4* __restrict__ C0 = (const float4*)ws;
    const float4* __restrict__ C1 = (const float4*)(ws + 4 * (size_t)NPT);

    v2f cur[3], old_[3];
    v2f ca[3], cb[3];                       // {A11,A66}, {A66,A22}
    float a12p66[3], a16[3], a26[3], gs[3];
    int gidx[3];

#pragma unroll
    for (int j = 0; j < 3; ++j) {
        int gx = gx0 + r0;
        int gy = gy0 + c0 + j;
        bool d = (unsigned)gx < (unsigned)NXg && (unsigned)gy < (unsigned)NYg;
        int g = d ? gx * NYg + gy : 0;
        gidx[j] = g;
        float4 st = d ? inS[g] : make_float4(0, 0, 0, 0);
        v2f c; c[0] = st.x; c[1] = st.y;
        v2f o; o[0] = st.z; o[1] = st.w;
        cur[j] = c; old_[j] = o;
        float4 k0 = d ? C0[g] : make_float4(0, 0, 0, 0);
        float4 k1 = d ? C1[g] : make_float4(0, 0, 0, 0);
        v2f t; t[0] = k0.x; t[1] = k1.y; ca[j] = t;   // {A11, A66}
        v2f u; u[0] = k1.y; u[1] = k0.y; cb[j] = u;   // {A66, A22}
        a12p66[j] = k0.z; a16[j] = k0.w; a26[j] = k1.x; gs[j] = k1.z;
    }

    // preload all step source values; step loop FULLY UNROLLED -> registers
    const int t0 = L * KSTEPS;
    float sigv[KSTEPS];
#pragma unroll
    for (int k = 0; k < KSTEPS; ++k) sigv[k] = sig[t0 + k];

    // clamped vertical halo rows (trapezoid garbage-tolerance at rim)
    const int rm = (r0 > 0) ? r0 - 1 : 0;
    const int rp = (r0 + 1 < TS) ? r0 + 1 : TS - 1;

    // owned core: rows [12,36) -> tx in [12,36); cols [12,36) -> ty in [4,12)
    const bool owned = (tx >= 12) && (tx < 36) && (ty >= 4) && (ty < 12);

    // publish initial values into buffer 0
#pragma unroll
    for (int j = 0; j < 3; ++j)
        sb[0][r0][c0 + j] = cur[j];
    LDS_BARRIER();

    v2f c20; c20[0] = 2.0f; c20[1] = 0.0f;
    v2f c02; c02[0] = 0.0f; c02[1] = 2.0f;
    const v2f m2 = vbc(-2.0f);
    const v2f qt = vbc(0.25f);
    const v2f two = vbc(2.0f);

#pragma unroll
    for (int s = 1; s <= KSTEPS; ++s) {
        const v2f (*rb)[TS + 1] = sb[(s - 1) & 1];
        v2f (*wb)[TS + 1] = sb[s & 1];
        v2f vsig; vsig[0] = 0.0f; vsig[1] = sigv[s - 1];

        // 3x5 window: own row + DPP side cols; rows +-1 from LDS (6 b64)
        // with their side cols via DPP of the loaded values.
        v2f vm[5], vc[5], vp[5];
        vc[1] = cur[0]; vc[2] = cur[1]; vc[3] = cur[2];
        vc[0] = dpp_shift<ROW_SHR1>(cur[0], cur[2]);
        vc[4] = dpp_shift<ROW_SHL1>(cur[2], cur[0]);
        {
            v2f a0 = rb[rm][c0], a1 = rb[rm][c0 + 1], a2 = rb[rm][c0 + 2];
            vm[1] = a0; vm[2] = a1; vm[3] = a2;
            vm[0] = dpp_shift<ROW_SHR1>(a0, a2);
            vm[4] = dpp_shift<ROW_SHL1>(a2, a0);
        }
        {
            v2f b0 = rb[rp][c0], b1 = rb[rp][c0 + 1], b2 = rb[rp][c0 + 2];
            vp[1] = b0; vp[2] = b1; vp[3] = b2;
            vp[0] = dpp_shift<ROW_SHR1>(b0, b2);
            vp[4] = dpp_shift<ROW_SHL1>(b2, b0);
        }

        // horizontal differences for cross-derivs (rows rm, rp only)
        v2f dhm[3], dhp[3];
#pragma unroll
        for (int j = 0; j < 3; ++j) {
            dhm[j] = vm[j + 2] - vm[j];
            dhp[j] = vp[j + 2] - vp[j];
        }

#pragma unroll
        for (int j = 0; j < 3; ++j) {
            v2f c = vc[j + 1];
            v2f sxx = vfma(m2, c, vm[j + 1] + vp[j + 1]);  // pk
            v2f syy = vfma(m2, c, vc[j] + vc[j + 2]);      // pk
            v2f sxy = qt * (dhp[j] - dhm[j]);              // pk

            // t4 = {2*sxy.x + sxx.y, sxx.x}; t5 = {syy.y, 2*sxy.y + syy.x}
            v2f t4 = vfma(c20, vbc(sxy[0]), vswap(sxx));
            v2f t5 = vfma(c02, vbc(sxy[1]), vswap(syy));
            // L = {lux, luy}
            v2f Lv = ca[j] * sxx;
            Lv = vfma(cb[j], syy, Lv);
            Lv = vfma(vbc(a12p66[j]), vswap(sxy), Lv);
            Lv = vfma(vbc(a16[j]), t4, Lv);
            Lv = vfma(vbc(a26[j]), t5, Lv);
            // source on y only: {lux, sig*gs + luy} (exact: 0*gs+lux)
            Lv = vfma(vsig, vbc(gs[j]), Lv);
            // n = fma(2, c, L) - old
            v2f n = vfma(two, c, Lv) - old_[j];
            old_[j] = c;
            cur[j] = n;
        }

        // frame output at global t = t0 + s - 1; t%4==3 <=> s%4==0
        // (fire-and-forget: the step barrier does NOT drain vmcnt)
        if ((s & 3) == 0 && owned) {
            int f = 3 * L + (s >> 2) - 1;
            float* oux = out + (size_t)f * NPT;
            float* ouy = out + (size_t)(NFRAMES + f) * NPT;
#pragma unroll
            for (int j = 0; j < 3; ++j) {
                oux[gidx[j]] = cur[j][0];
                ouy[gidx[j]] = cur[j][1];
            }
        }

        // publish new values; final step's publish + barrier are dead
        if (s < KSTEPS) {
#pragma unroll
            for (int j = 0; j < 3; ++j)
                wb[r0][c0 + j] = cur[j];
            LDS_BARRIER();
        }
    }

    if (owned) {
#pragma unroll
        for (int j = 0; j < 3; ++j) {
            float4 st = make_float4(cur[j][0], cur[j][1], old_[j][0], old_[j][1]);
            outS[gidx[j]] = st;
        }
    }
}

extern "C" void kernel_launch(void* const* d_in, const int* in_sizes, int n_in,
                              void* d_out, int out_size, void* d_ws, size_t ws_size,
                              hipStream_t stream) {
    const float* lc11  = (const float*)d_in[0];
    const float* lc12  = (const float*)d_in[1];
    const float* lc16  = (const float*)d_in[2];
    const float* lc22  = (const float*)d_in[3];
    const float* lc26  = (const float*)d_in[4];
    const float* lc66  = (const float*)d_in[5];
    const float* gauss = (const float*)d_in[6];
    const float* sig   = (const float*)d_in[7];

    float* ws  = (float*)d_ws;
    float* out = (float*)d_out;

    setup_kernel<<<(NPT + 255) / 256, 256, 0, stream>>>(lc11, lc12, lc16, lc22,
                                                        lc26, lc66, gauss, ws);

    float4* set0 = (float4*)(ws + 8 * (size_t)NPT);
    float4* set1 = (float4*)(ws + 12 * (size_t)NPT);

    dim3 grid(NXg / OWN, NYg / OWN);  // 16x16 = 256 blocks, 1 per CU, 12 waves
    for (int L = 0; L < NLAUNCH; ++L) {
        float4* iS = (L & 1) ? set1 : set0;
        float4* oS = (L & 1) ? set0 : set1;
        fused_kernel<<<grid, NTH, 0, stream>>>(ws, sig, iS, oS, out, L);
    }
}